// Round 1
// baseline (357.255 us; speedup 1.0000x reference)
//
#include <hip/hip_runtime.h>
#include <math.h>

#define B 4
#define C 256
#define N 512
#define CQ 64

// 180/(pi*15)
__device__ __constant__ float FACTOR = 3.81971863420548805845f;
// ln(10000)/32  (div_term[i] = exp(-i * this), i = 0..31)
#define DIVK 0.28782313662425575f

// ---------------- K1: projections ----------------
// xq[b][n][o]  = sum_c Wkp[o][c] * x[b][c][n]                (B,N,CQ)
// Kt[b][o][m]  = sum_c Wk[o][c]*x[b][c][m] + Wkp[o][c]*pca   (B,CQ,N)
// vsum[b][o][n]= sum_c Wv[o][c]*x + Wvp[o][c]*pca            (B,C,N)
__global__ __launch_bounds__(256) void k_proj(
    const float* __restrict__ x, const float* __restrict__ pca,
    const float* __restrict__ Wkp, const float* __restrict__ Wk,
    const float* __restrict__ Wv, const float* __restrict__ Wvp,
    float* __restrict__ xq, float* __restrict__ Kt, float* __restrict__ vsum)
{
    const int b  = blockIdx.x / (N / 16);
    const int n0 = (blockIdx.x % (N / 16)) * 16;
    __shared__ float xs[C][16];
    __shared__ float ps[C][16];
    const float* xb = x + b * C * N;
    const float* pb = pca + b * C * N;
    for (int idx = threadIdx.x; idx < C * 16; idx += 256) {
        int c = idx >> 4, nl = idx & 15;
        xs[c][nl] = xb[c * N + n0 + nl];
        ps[c][nl] = pb[c * N + n0 + nl];
    }
    __syncthreads();
    const int nl = threadIdx.x & 15;
    const int og = threadIdx.x >> 4;  // 0..15
    // xq and Kt: 64 outputs, 4 per thread
    for (int j = 0; j < 4; ++j) {
        int o = og + 16 * j;
        float aq = 0.f, ak = 0.f;
        const float* wkp = Wkp + o * C;
        const float* wk  = Wk + o * C;
        for (int c = 0; c < C; ++c) {
            float xv = xs[c][nl], pv = ps[c][nl];
            aq = fmaf(wkp[c], xv, aq);
            ak = fmaf(wk[c], xv, ak);
            ak = fmaf(wkp[c], pv, ak);
        }
        xq[(b * N + n0 + nl) * CQ + o] = aq;
        Kt[(b * CQ + o) * N + n0 + nl] = ak;
    }
    // vsum: 256 outputs, 16 per thread
    for (int j = 0; j < 16; ++j) {
        int o = og + 16 * j;
        float av = 0.f;
        const float* wv  = Wv + o * C;
        const float* wvp = Wvp + o * C;
        for (int c = 0; c < C; ++c) {
            av = fmaf(wv[c], xs[c][nl], av);
            av = fmaf(wvp[c], ps[c][nl], av);
        }
        vsum[(b * C + o) * N + n0 + nl] = av;
    }
}

// ---------------- K2a: fold e2 into Kt ----------------
// Kt[b][o][m] += sum_k emb2_W[o][k] * embvec(angle_pca[b][m])[k] + emb2_b[o]
__global__ __launch_bounds__(256) void k_e2(
    const float* __restrict__ angle_pca,
    const float* __restrict__ emb2_W, const float* __restrict__ emb2_b,
    float* __restrict__ Kt)
{
    const int b  = blockIdx.x / (N / 4);
    const int m0 = (blockIdx.x % (N / 4)) * 4;
    __shared__ float emb[4][CQ];
    const int sub = threadIdx.x >> 6;  // 0..3 (which m)
    const int o   = threadIdx.x & 63;
    if (o < 32) {
        float a = angle_pca[b * N + m0 + sub] * FACTOR;
        float d = expf(-(float)o * DIVK);
        float s, c;
        sincosf(a * d, &s, &c);
        emb[sub][2 * o]     = s;
        emb[sub][2 * o + 1] = c;
    }
    __syncthreads();
    float acc = emb2_b[o];
    const float* w = emb2_W + o * CQ;
    for (int k = 0; k < CQ; ++k) acc = fmaf(w[k], emb[sub][k], acc);
    Kt[(b * CQ + o) * N + m0 + sub] += acc;
}

// ---------------- K2b: q1 = xq @ emb1_W, c1 = xq . emb1_b ----------------
__global__ __launch_bounds__(256) void k_q1(
    const float* __restrict__ xq,
    const float* __restrict__ emb1_W, const float* __restrict__ emb1_b,
    float* __restrict__ q1, float* __restrict__ c1)
{
    const int b  = blockIdx.x / (N / 4);
    const int n0 = (blockIdx.x % (N / 4)) * 4;
    __shared__ float xs[4][CQ];
    const int sub = threadIdx.x >> 6;
    const int k   = threadIdx.x & 63;
    xs[sub][k] = xq[(b * N + n0 + sub) * CQ + k];
    __syncthreads();
    float acc = 0.f;
    for (int j = 0; j < CQ; ++j) acc = fmaf(xs[sub][j], emb1_W[j * CQ + k], acc);
    q1[(b * N + n0 + sub) * CQ + k] = acc;
    if (k == 0) {
        float cc = 0.f;
        for (int j = 0; j < CQ; ++j) cc = fmaf(xs[sub][j], emb1_b[j], cc);
        c1[b * N + n0 + sub] = cc;
    }
}

// ---------------- K3: energy + row softmax ----------------
// E[b][n][m] = softmax_m( xq.Kt[:,m] + sum_i q1[2i]*sin + q1[2i+1]*cos + c1 )
__global__ __launch_bounds__(256) void k_energy(
    const float* __restrict__ xq, const float* __restrict__ q1,
    const float* __restrict__ c1, const float* __restrict__ Kt,
    const float* __restrict__ angle_lrf, float* __restrict__ E)
{
    const int b = blockIdx.x / N;
    const int n = blockIdx.x % N;
    __shared__ float xs[CQ], qs[CQ], divs[32];
    __shared__ float red[256];
    const int t = threadIdx.x;
    if (t < CQ) {
        xs[t] = xq[(b * N + n) * CQ + t];
        qs[t] = q1[(b * N + n) * CQ + t];
    }
    if (t >= 64 && t < 96) divs[t - 64] = expf(-(float)(t - 64) * DIVK);
    __syncthreads();
    const float cc = c1[b * N + n];
    const float* ktb = Kt + b * CQ * N;
    const float* al  = angle_lrf + (b * N + n) * N;
    float e[2];
    for (int r = 0; r < 2; ++r) {
        int m = t + r * 256;
        float acc = cc;
        for (int o = 0; o < CQ; ++o) acc = fmaf(xs[o], ktb[o * N + m], acc);
        float a = al[m] * FACTOR;
        for (int i = 0; i < 32; ++i) {
            float s, cz;
            sincosf(a * divs[i], &s, &cz);
            acc = fmaf(qs[2 * i], s, acc);
            acc = fmaf(qs[2 * i + 1], cz, acc);
        }
        e[r] = acc;
    }
    // block-reduce max
    float mx = fmaxf(e[0], e[1]);
    red[t] = mx;
    __syncthreads();
    for (int s = 128; s > 0; s >>= 1) {
        if (t < s) red[t] = fmaxf(red[t], red[t + s]);
        __syncthreads();
    }
    mx = red[0];
    __syncthreads();
    float e0 = expf(e[0] - mx), e1v = expf(e[1] - mx);
    red[t] = e0 + e1v;
    __syncthreads();
    for (int s = 128; s > 0; s >>= 1) {
        if (t < s) red[t] += red[t + s];
        __syncthreads();
    }
    const float inv = 1.f / red[0];
    float* Eb = E + (b * N + n) * N;
    Eb[t]       = e0 * inv;
    Eb[t + 256] = e1v * inv;
}

// ---------------- K4: column sums -> reciprocal ----------------
__global__ __launch_bounds__(256) void k_colsum(
    const float* __restrict__ E, float* __restrict__ rc)
{
    const int b  = blockIdx.x / (N / 32);
    const int m0 = (blockIdx.x % (N / 32)) * 32;
    const int ml = threadIdx.x & 31, ng = threadIdx.x >> 5;
    float acc = 0.f;
    const float* Eb = E + b * N * N;
    for (int n = ng; n < N; n += 8) acc += Eb[n * N + m0 + ml];
    __shared__ float red[8][32];
    red[ng][ml] = acc;
    __syncthreads();
    if (ng == 0) {
        float s = 0.f;
        for (int g = 0; g < 8; ++g) s += red[g][ml];
        rc[b * N + m0 + ml] = 1.f / (1e-12f + s);
    }
}

// ---------------- K5: xr = 0.5 * vsum @ (E * rc) ----------------
__global__ __launch_bounds__(256) void k_xr(
    const float* __restrict__ vsum, const float* __restrict__ E,
    const float* __restrict__ rc, float* __restrict__ xr)
{
    const int bid = blockIdx.x;
    const int b  = bid / 32;
    const int ot = (bid / 8) % 4;
    const int mt = bid % 8;
    const int o0 = ot * 64, m0 = mt * 64;
    __shared__ float vs[64][33];
    __shared__ float es[32][65];
    __shared__ float rcs[64];
    const int t = threadIdx.x;
    if (t < 64) rcs[t] = rc[b * N + m0 + t];
    const int to = t & 15, tm = t >> 4;
    float acc[4][4] = {};
    for (int nc = 0; nc < N; nc += 32) {
        __syncthreads();
        for (int idx = t; idx < 64 * 32; idx += 256) {
            int o = idx >> 5, nl = idx & 31;
            vs[o][nl] = vsum[(b * C + o0 + o) * N + nc + nl];
        }
        for (int idx = t; idx < 32 * 64; idx += 256) {
            int nl = idx >> 6, m = idx & 63;
            es[nl][m] = E[(b * N + nc + nl) * N + m0 + m] * rcs[m];
        }
        __syncthreads();
        for (int nl = 0; nl < 32; ++nl) {
            float ev[4], vv[4];
            for (int j = 0; j < 4; ++j) ev[j] = es[nl][tm * 4 + j];
            for (int i = 0; i < 4; ++i) vv[i] = vs[to * 4 + i][nl];
            for (int i = 0; i < 4; ++i)
                for (int j = 0; j < 4; ++j)
                    acc[i][j] = fmaf(vv[i], ev[j], acc[i][j]);
        }
    }
    for (int i = 0; i < 4; ++i)
        for (int j = 0; j < 4; ++j)
            xr[(b * C + o0 + to * 4 + i) * N + m0 + tm * 4 + j] = 0.5f * acc[i][j];
}

// ---------------- K6: z = lin_W @ (x - xr) + lin_b ----------------
__global__ __launch_bounds__(256) void k_z(
    const float* __restrict__ x, const float* __restrict__ xr,
    const float* __restrict__ lin_W, const float* __restrict__ lin_b,
    float* __restrict__ z)
{
    const int bid = blockIdx.x;
    const int b  = bid / 32;
    const int ot = (bid / 8) % 4;
    const int nt = bid % 8;
    const int o0 = ot * 64, n0 = nt * 64;
    __shared__ float wsh[64][33];
    __shared__ float ds[32][65];
    const int t = threadIdx.x;
    const int to = t & 15, tn = t >> 4;
    float acc[4][4] = {};
    for (int cc = 0; cc < C; cc += 32) {
        __syncthreads();
        for (int idx = t; idx < 64 * 32; idx += 256) {
            int o = idx >> 5, cl = idx & 31;
            wsh[o][cl] = lin_W[(o0 + o) * C + cc + cl];
        }
        for (int idx = t; idx < 32 * 64; idx += 256) {
            int cl = idx >> 6, nl = idx & 63;
            int g = (b * C + cc + cl) * N + n0 + nl;
            ds[cl][nl] = x[g] - xr[g];
        }
        __syncthreads();
        for (int cl = 0; cl < 32; ++cl) {
            float dv[4], wv[4];
            for (int j = 0; j < 4; ++j) dv[j] = ds[cl][tn * 4 + j];
            for (int i = 0; i < 4; ++i) wv[i] = wsh[to * 4 + i][cl];
            for (int i = 0; i < 4; ++i)
                for (int j = 0; j < 4; ++j)
                    acc[i][j] = fmaf(wv[i], dv[j], acc[i][j]);
        }
    }
    for (int i = 0; i < 4; ++i) {
        float bb = lin_b[o0 + to * 4 + i];
        for (int j = 0; j < 4; ++j)
            z[(b * C + o0 + to * 4 + i) * N + n0 + tn * 4 + j] = acc[i][j] + bb;
    }
}

// ---------------- K7: BN stats per channel ----------------
__global__ __launch_bounds__(256) void k_stats(
    const float* __restrict__ z, float* __restrict__ stat)
{
    const int c = blockIdx.x;
    const int t = threadIdx.x;
    float s = 0.f, s2 = 0.f;
    for (int i = t; i < B * N; i += 256) {
        int b = i >> 9, n = i & 511;
        float v = z[(b * C + c) * N + n];
        s += v;
        s2 = fmaf(v, v, s2);
    }
    __shared__ float r1[256], r2[256];
    r1[t] = s; r2[t] = s2;
    __syncthreads();
    for (int st = 128; st > 0; st >>= 1) {
        if (t < st) { r1[t] += r1[t + st]; r2[t] += r2[t + st]; }
        __syncthreads();
    }
    if (t == 0) { stat[c] = r1[0]; stat[C + c] = r2[0]; }
}

// ---------------- K8: BN apply + gelu + residual ----------------
__global__ __launch_bounds__(256) void k_final(
    const float* __restrict__ x, const float* __restrict__ z,
    const float* __restrict__ stat, const float* __restrict__ gamma,
    const float* __restrict__ beta, float* __restrict__ out)
{
    const int idx = blockIdx.x * 256 + threadIdx.x;  // over B*C*N
    const float v = z[idx];
    const int c = (idx >> 9) & 255;
    const float mu  = stat[c] * (1.f / (B * N));
    const float var = stat[C + c] * (1.f / (B * N)) - mu * mu;
    const float y = gamma[c] * (v - mu) * rsqrtf(var + 1e-5f) + beta[c];
    const float g = 0.5f * y * (1.f + erff(y * 0.70710678118654752f));
    out[idx] = x[idx] + g;
}

// ---------------- K9: point_relation ----------------
__global__ __launch_bounds__(256) void k_pr(
    const float* __restrict__ E, const float* __restrict__ rc,
    float* __restrict__ out)
{
    const int i = blockIdx.x * 256 + threadIdx.x;  // B*N
    const int b = i >> 9, m = i & 511;
    out[B * C * N + i] = E[(b * N) * N + m] * rc[b * N + m];
}

extern "C" void kernel_launch(void* const* d_in, const int* in_sizes, int n_in,
                              void* d_out, int out_size, void* d_ws, size_t ws_size,
                              hipStream_t stream)
{
    const float* x         = (const float*)d_in[0];
    const float* pca       = (const float*)d_in[1];
    const float* angle_lrf = (const float*)d_in[2];
    const float* angle_pca = (const float*)d_in[3];
    const float* Wkp       = (const float*)d_in[4];
    const float* Wk        = (const float*)d_in[5];
    const float* Wv        = (const float*)d_in[6];
    const float* Wvp       = (const float*)d_in[7];
    const float* e1W       = (const float*)d_in[8];
    const float* e1b       = (const float*)d_in[9];
    const float* e2W       = (const float*)d_in[10];
    const float* e2b       = (const float*)d_in[11];
    const float* linW      = (const float*)d_in[12];
    const float* linb      = (const float*)d_in[13];
    const float* gamma     = (const float*)d_in[14];
    const float* beta      = (const float*)d_in[15];

    float* ws   = (float*)d_ws;
    float* xq   = ws;               // B*N*CQ   = 131072
    float* q1   = xq + 131072;      // 131072
    float* c1   = q1 + 131072;      // 2048
    float* Kt   = c1 + 2048;        // 131072
    float* vsum = Kt + 131072;      // 524288
    float* E    = vsum + 524288;    // 1048576
    float* rc   = E + 1048576;      // 2048
    float* xr   = rc + 2048;        // 524288
    float* z    = xr + 524288;      // 524288
    float* stat = z + 524288;       // 512
    float* out  = (float*)d_out;

    k_proj<<<B * (N / 16), 256, 0, stream>>>(x, pca, Wkp, Wk, Wv, Wvp, xq, Kt, vsum);
    k_e2<<<B * (N / 4), 256, 0, stream>>>(angle_pca, e2W, e2b, Kt);
    k_q1<<<B * (N / 4), 256, 0, stream>>>(xq, e1W, e1b, q1, c1);
    k_energy<<<B * N, 256, 0, stream>>>(xq, q1, c1, Kt, angle_lrf, E);
    k_colsum<<<B * (N / 32), 256, 0, stream>>>(E, rc);
    k_xr<<<B * 4 * 8, 256, 0, stream>>>(vsum, E, rc, xr);
    k_z<<<B * 4 * 8, 256, 0, stream>>>(x, xr, linW, linb, z);
    k_stats<<<C, 256, 0, stream>>>(z, stat);
    k_final<<<(B * C * N) / 256, 256, 0, stream>>>(x, z, stat, gamma, beta, out);
    k_pr<<<(B * N) / 256, 256, 0, stream>>>(E, rc, out);
}

// Round 2
// 110.449 us; speedup vs baseline: 3.2346x; 3.2346x over previous
//
#include <hip/hip_runtime.h>
#include <math.h>

#define PROWS 704
#define FCT 3.81971863420548805845f
#define DIVK 0.28782313662425575f

using bf16x8 = __attribute__((ext_vector_type(8))) short;
using f32x4  = __attribute__((ext_vector_type(4))) float;

__device__ inline short f2bf(float f) {
    union { float f; unsigned u; } v; v.f = f;
    unsigned r = v.u + 0x7FFFu + ((v.u >> 16) & 1u);
    return (short)(r >> 16);
}
__device__ inline float bf2f(short s) {
    union { unsigned u; float f; } v;
    v.u = ((unsigned)(unsigned short)s) << 16;
    return v.f;
}
__device__ inline unsigned pk2(float lo, float hi) {
    return ((unsigned)(unsigned short)f2bf(hi) << 16) | (unsigned)(unsigned short)f2bf(lo);
}

// ---- prep: Wcat bf16 [704][512] ----
__global__ __launch_bounds__(256) void k_prep_w(
    const float* __restrict__ Wkp, const float* __restrict__ Wk,
    const float* __restrict__ Wv, const float* __restrict__ Wvp,
    const float* __restrict__ linW, const float* __restrict__ e1W,
    short* __restrict__ Wcatb)
{
    const int r = blockIdx.x;  // 0..703
    for (int k = threadIdx.x; k < 512; k += 256) {
        float v = 0.f;
        if (r < 64) { if (k < 256) v = Wkp[r*256 + k]; }
        else if (r < 128) { int o = r-64;  v = (k<256) ? Wk[o*256+k]  : Wkp[o*256 + k-256]; }
        else if (r < 384) { int o = r-128; v = (k<256) ? Wv[o*256+k]  : Wvp[o*256 + k-256]; }
        else if (r < 640) { int o = r-384; if (k<256) v = linW[o*256+k]; }
        else {
            int o = r-640;
            if (k < 256) {
                float a = 0.f;
                for (int j = 0; j < 64; ++j) a = fmaf(e1W[j*64 + o], Wkp[j*256 + k], a);
                v = a;
            }
        }
        Wcatb[(size_t)r*512 + k] = f2bf(v);
    }
}

// ---- prep: InT bf16 [b][n][k]  (k<256: x, else pca; transposed) ----
__global__ __launch_bounds__(256) void k_prep_in(
    const float* __restrict__ x, const float* __restrict__ pca, short* __restrict__ InTb)
{
    const int bid = blockIdx.x;           // 4b x 8kt x 8nt = 256
    const int b  = bid >> 6;
    const int kt = (bid >> 3) & 7;
    const int nt = bid & 7;
    const int k0 = kt*64, n0 = nt*64;
    __shared__ float ts[64][65];
    const float* src = (k0 < 256) ? (x + ((size_t)b*256 + k0)*512)
                                  : (pca + ((size_t)b*256 + (k0-256))*512);
    #pragma unroll
    for (int i = 0; i < 16; ++i) {
        int idx = threadIdx.x + 256*i;
        int r = idx >> 6, c = idx & 63;
        ts[r][c] = src[(size_t)r*512 + n0 + c];
    }
    __syncthreads();
    short* dst = InTb + (size_t)b*512*512;
    #pragma unroll
    for (int i = 0; i < 16; ++i) {
        int idx = threadIdx.x + 256*i;
        int n = idx >> 6, k = idx & 63;
        dst[(size_t)(n0+n)*512 + k0 + k] = f2bf(ts[k][n]);
    }
}

// ---- big GEMM: P[b][704][512] = Wcat @ [x;pca], MFMA bf16, direct-L2 frags ----
__global__ __launch_bounds__(256) void k_gemm1(
    const short* __restrict__ Wcatb, const short* __restrict__ InTb,
    float* __restrict__ P, short* __restrict__ vsumb)
{
    const int bid = blockIdx.x;            // 4 x 11 x 16 = 704
    const int b  = bid / 176;
    const int rt = (bid / 16) % 11;
    const int ct = bid % 16;
    const int r0 = rt*64, c0 = ct*32;
    const int w = threadIdx.x >> 6, lane = threadIdx.x & 63;
    const int lr = lane & 15, lg = lane >> 4;

    const short* ap  = Wcatb + (size_t)(r0 + w*16 + lr)*512 + 8*lg;
    const short* bp0 = InTb + (size_t)b*512*512 + (size_t)(c0 + lr)*512 + 8*lg;
    const short* bp1 = bp0 + 16*512;

    f32x4 acc0 = {0.f,0.f,0.f,0.f}, acc1 = {0.f,0.f,0.f,0.f};
    #pragma unroll 4
    for (int kk = 0; kk < 512; kk += 32) {
        bf16x8 a  = *(const bf16x8*)(ap  + kk);
        bf16x8 b0 = *(const bf16x8*)(bp0 + kk);
        bf16x8 b1 = *(const bf16x8*)(bp1 + kk);
        acc0 = __builtin_amdgcn_mfma_f32_16x16x32_bf16(a, b0, acc0, 0, 0, 0);
        acc1 = __builtin_amdgcn_mfma_f32_16x16x32_bf16(a, b1, acc1, 0, 0, 0);
    }
    float* Pb = P + (size_t)b*PROWS*512;
    const int rowb = r0 + w*16 + lg*4;
    const int col0 = c0 + lr;
    #pragma unroll
    for (int j = 0; j < 4; ++j) {
        Pb[(size_t)(rowb+j)*512 + col0]      = acc0[j];
        Pb[(size_t)(rowb+j)*512 + col0 + 16] = acc1[j];
    }
    if (r0 >= 128 && r0 < 384) {   // vsum rows -> bf16 copy for xr MFMA
        short* vb = vsumb + (size_t)b*256*512 + (size_t)(rowb-128)*512;
        #pragma unroll
        for (int j = 0; j < 4; ++j) {
            vb[(size_t)j*512 + col0]      = f2bf(acc0[j]);
            vb[(size_t)j*512 + col0 + 16] = f2bf(acc1[j]);
        }
    }
}

// ---- fold e2 projection into Kt rows of P (bias dropped: softmax-invariant) ----
__global__ __launch_bounds__(256) void k_e2(
    const float* __restrict__ angle_pca, const float* __restrict__ e2W,
    float* __restrict__ P)
{
    const int b  = blockIdx.x >> 7;        // 4 x 128
    const int m0 = (blockIdx.x & 127) * 4;
    __shared__ float emb[4][64];
    const int sub = threadIdx.x >> 6;
    const int o   = threadIdx.x & 63;
    if (o < 32) {
        float a = angle_pca[b*512 + m0 + sub] * FCT;
        float s, c;
        sincosf(a * expf(-(float)o * DIVK), &s, &c);
        emb[sub][2*o] = s; emb[sub][2*o+1] = c;
    }
    __syncthreads();
    float acc = 0.f;
    const float* wrow = e2W + o*64;
    #pragma unroll 8
    for (int k = 0; k < 64; ++k) acc = fmaf(wrow[k], emb[sub][k], acc);
    P[(size_t)b*PROWS*512 + (size_t)(64+o)*512 + m0 + sub] += acc;
}

// ---- energy + row softmax; 4 rows per block; writes ET[m][n] bf16 ----
__global__ __launch_bounds__(256) void k_energy(
    const float* __restrict__ P, const float* __restrict__ angle_lrf,
    short* __restrict__ ETb)
{
    const int b  = blockIdx.x >> 7;        // 4 x 128
    const int n0 = (blockIdx.x & 127) * 4;
    const float* Pb = P + (size_t)b*PROWS*512;
    __shared__ float xs[4][64], qs[4][64], divs[32];
    __shared__ float4 red[256];
    const int t = threadIdx.x;
    if (t < 64) {
        #pragma unroll
        for (int i = 0; i < 4; ++i) {
            xs[i][t] = Pb[(size_t)t*512 + n0 + i];
            qs[i][t] = Pb[(size_t)(640+t)*512 + n0 + i];
        }
    } else if (t < 96) {
        divs[t-64] = __expf(-(float)(t-64) * DIVK);
    }
    __syncthreads();
    float e0[4], e1v[4];
    #pragma unroll
    for (int r = 0; r < 2; ++r) {
        const int m = t + 256*r;
        float acc[4] = {0.f, 0.f, 0.f, 0.f};
        const float* kp = Pb + (size_t)64*512 + m;
        #pragma unroll 8
        for (int o = 0; o < 64; ++o) {
            float kv = kp[(size_t)o*512];
            #pragma unroll
            for (int i = 0; i < 4; ++i) acc[i] = fmaf(xs[i][o], kv, acc[i]);
        }
        float a[4];
        #pragma unroll
        for (int i = 0; i < 4; ++i)
            a[i] = angle_lrf[((size_t)b*512 + n0 + i)*512 + m] * FCT;
        for (int j = 0; j < 32; ++j) {
            float d = divs[j];
            #pragma unroll
            for (int i = 0; i < 4; ++i) {
                float arg = a[i]*d;
                float s = __sinf(arg), c = __cosf(arg);
                acc[i] = fmaf(qs[i][2*j], s, fmaf(qs[i][2*j+1], c, acc[i]));
            }
        }
        #pragma unroll
        for (int i = 0; i < 4; ++i) { if (r == 0) e0[i] = acc[i]; else e1v[i] = acc[i]; }
    }
    float4 v;
    v.x = fmaxf(e0[0], e1v[0]); v.y = fmaxf(e0[1], e1v[1]);
    v.z = fmaxf(e0[2], e1v[2]); v.w = fmaxf(e0[3], e1v[3]);
    red[t] = v; __syncthreads();
    for (int s = 128; s > 0; s >>= 1) {
        if (t < s) {
            float4 o = red[t+s], m2 = red[t];
            m2.x = fmaxf(m2.x,o.x); m2.y = fmaxf(m2.y,o.y);
            m2.z = fmaxf(m2.z,o.z); m2.w = fmaxf(m2.w,o.w);
            red[t] = m2;
        }
        __syncthreads();
    }
    float4 mx = red[0]; __syncthreads();
    float p0[4], p1[4];
    p0[0] = __expf(e0[0]-mx.x); p0[1] = __expf(e0[1]-mx.y);
    p0[2] = __expf(e0[2]-mx.z); p0[3] = __expf(e0[3]-mx.w);
    p1[0] = __expf(e1v[0]-mx.x); p1[1] = __expf(e1v[1]-mx.y);
    p1[2] = __expf(e1v[2]-mx.z); p1[3] = __expf(e1v[3]-mx.w);
    v.x = p0[0]+p1[0]; v.y = p0[1]+p1[1]; v.z = p0[2]+p1[2]; v.w = p0[3]+p1[3];
    red[t] = v; __syncthreads();
    for (int s = 128; s > 0; s >>= 1) {
        if (t < s) {
            float4 o = red[t+s];
            red[t].x += o.x; red[t].y += o.y; red[t].z += o.z; red[t].w += o.w;
        }
        __syncthreads();
    }
    float4 tot = red[0];
    float i0 = 1.f/tot.x, i1 = 1.f/tot.y, i2 = 1.f/tot.z, i3 = 1.f/tot.w;
    short* Eb = ETb + (size_t)b*512*512;
    Eb[(size_t)t*512 + n0+0] = f2bf(p0[0]*i0);
    Eb[(size_t)t*512 + n0+1] = f2bf(p0[1]*i1);
    Eb[(size_t)t*512 + n0+2] = f2bf(p0[2]*i2);
    Eb[(size_t)t*512 + n0+3] = f2bf(p0[3]*i3);
    Eb[(size_t)(t+256)*512 + n0+0] = f2bf(p1[0]*i0);
    Eb[(size_t)(t+256)*512 + n0+1] = f2bf(p1[1]*i1);
    Eb[(size_t)(t+256)*512 + n0+2] = f2bf(p1[2]*i2);
    Eb[(size_t)(t+256)*512 + n0+3] = f2bf(p1[3]*i3);
}

// ---- column sums of E == row sums of ET -> rc = 1/(1e-12+s) ----
__global__ __launch_bounds__(256) void k_colsum(
    const short* __restrict__ ETb, float* __restrict__ rc)
{
    const int row  = blockIdx.x*4 + (threadIdx.x >> 6);   // b*512+m, 2048 total
    const int lane = threadIdx.x & 63;
    const uint4 u4 = *(const uint4*)(ETb + (size_t)row*512 + lane*8);
    float s = 0.f;
    unsigned uu[4] = {u4.x, u4.y, u4.z, u4.w};
    #pragma unroll
    for (int i = 0; i < 4; ++i) {
        union { unsigned u; float f; } lo, hi;
        lo.u = uu[i] << 16; hi.u = uu[i] & 0xFFFF0000u;
        s += lo.f + hi.f;
    }
    #pragma unroll
    for (int off = 32; off > 0; off >>= 1) s += __shfl_xor(s, off, 64);
    if (lane == 0) rc[row] = 1.f / (1e-12f + s);
}

// ---- xr = 0.5*rc[m]*(vsum @ E), MFMA, store transposed bf16 xrT[m][o] ----
__global__ __launch_bounds__(256) void k_xr2(
    const short* __restrict__ vsumb, const short* __restrict__ ETb,
    const float* __restrict__ rc, short* __restrict__ xrT)
{
    const int bid = blockIdx.x;            // 4 x 4 x 16 = 256
    const int b  = bid / 64;
    const int rt = (bid / 16) % 4;
    const int ct = bid % 16;
    const int r0 = rt*64, c0 = ct*32;
    const int w = threadIdx.x >> 6, lane = threadIdx.x & 63;
    const int lr = lane & 15, lg = lane >> 4;
    const short* ap  = vsumb + (size_t)b*256*512 + (size_t)(r0 + w*16 + lr)*512 + 8*lg;
    const short* bp0 = ETb + (size_t)b*512*512 + (size_t)(c0 + lr)*512 + 8*lg;
    const short* bp1 = bp0 + 16*512;
    f32x4 acc0 = {0.f,0.f,0.f,0.f}, acc1 = {0.f,0.f,0.f,0.f};
    #pragma unroll 4
    for (int kk = 0; kk < 512; kk += 32) {
        bf16x8 a  = *(const bf16x8*)(ap  + kk);
        bf16x8 b0 = *(const bf16x8*)(bp0 + kk);
        bf16x8 b1 = *(const bf16x8*)(bp1 + kk);
        acc0 = __builtin_amdgcn_mfma_f32_16x16x32_bf16(a, b0, acc0, 0, 0, 0);
        acc1 = __builtin_amdgcn_mfma_f32_16x16x32_bf16(a, b1, acc1, 0, 0, 0);
    }
    const int rowb = r0 + w*16 + lg*4;     // o base
    const int m0 = c0 + lr, m1 = m0 + 16;
    const float s0 = 0.5f * rc[b*512 + m0];
    const float s1 = 0.5f * rc[b*512 + m1];
    short* xb = xrT + (size_t)b*512*256;
    uint2 u;
    u.x = pk2(acc0[0]*s0, acc0[1]*s0);
    u.y = pk2(acc0[2]*s0, acc0[3]*s0);
    *(uint2*)(xb + (size_t)m0*256 + rowb) = u;
    u.x = pk2(acc1[0]*s1, acc1[1]*s1);
    u.y = pk2(acc1[2]*s1, acc1[3]*s1);
    *(uint2*)(xb + (size_t)m1*256 + rowb) = u;
}

// ---- z = linx - linW @ xr + lin_b   (linx = P rows 384..639) ----
__global__ __launch_bounds__(256) void k_z2(
    const short* __restrict__ Wcatb, const short* __restrict__ xrT,
    const float* __restrict__ P, const float* __restrict__ lin_b,
    float* __restrict__ z)
{
    const int bid = blockIdx.x;            // 4 x 4 x 16 = 256
    const int b  = bid / 64;
    const int rt = (bid / 16) % 4;
    const int ct = bid % 16;
    const int r0 = rt*64, c0 = ct*32;
    const int w = threadIdx.x >> 6, lane = threadIdx.x & 63;
    const int lr = lane & 15, lg = lane >> 4;
    const short* ap  = Wcatb + (size_t)(384 + r0 + w*16 + lr)*512 + 8*lg;
    const short* bp0 = xrT + (size_t)b*512*256 + (size_t)(c0 + lr)*256 + 8*lg;
    const short* bp1 = bp0 + 16*256;
    f32x4 acc0 = {0.f,0.f,0.f,0.f}, acc1 = {0.f,0.f,0.f,0.f};
    #pragma unroll
    for (int kk = 0; kk < 256; kk += 32) {
        bf16x8 a  = *(const bf16x8*)(ap  + kk);
        bf16x8 b0 = *(const bf16x8*)(bp0 + kk);
        bf16x8 b1 = *(const bf16x8*)(bp1 + kk);
        acc0 = __builtin_amdgcn_mfma_f32_16x16x32_bf16(a, b0, acc0, 0, 0, 0);
        acc1 = __builtin_amdgcn_mfma_f32_16x16x32_bf16(a, b1, acc1, 0, 0, 0);
    }
    const int rowb = r0 + w*16 + lg*4;
    const int col0 = c0 + lr;
    const float* Pb = P + (size_t)b*PROWS*512 + (size_t)384*512;
    float* zb = z + (size_t)b*256*512;
    #pragma unroll
    for (int j = 0; j < 4; ++j) {
        float lb = lin_b[rowb+j];
        zb[(size_t)(rowb+j)*512 + col0]      = Pb[(size_t)(rowb+j)*512 + col0]      - acc0[j] + lb;
        zb[(size_t)(rowb+j)*512 + col0 + 16] = Pb[(size_t)(rowb+j)*512 + col0 + 16] - acc1[j] + lb;
    }
}

// ---- BN stats per channel ----
__global__ __launch_bounds__(256) void k_stats(
    const float* __restrict__ z, float* __restrict__ stat)
{
    const int c = blockIdx.x;
    const int t = threadIdx.x;
    float s = 0.f, s2 = 0.f;
    for (int i = t; i < 2048; i += 256) {
        int b = i >> 9, n = i & 511;
        float v = z[((size_t)b*256 + c)*512 + n];
        s += v; s2 = fmaf(v, v, s2);
    }
    __shared__ float r1[256], r2[256];
    r1[t] = s; r2[t] = s2;
    __syncthreads();
    for (int st = 128; st > 0; st >>= 1) {
        if (t < st) { r1[t] += r1[t+st]; r2[t] += r2[t+st]; }
        __syncthreads();
    }
    if (t == 0) { stat[c] = r1[0]; stat[256 + c] = r2[0]; }
}

// ---- BN apply + exact gelu + residual ----
__global__ __launch_bounds__(256) void k_final(
    const float* __restrict__ x, const float* __restrict__ z,
    const float* __restrict__ stat, const float* __restrict__ gamma,
    const float* __restrict__ beta, float* __restrict__ out)
{
    const int idx = blockIdx.x*256 + threadIdx.x;
    const float v = z[idx];
    const int c = (idx >> 9) & 255;
    const float mu  = stat[c] * (1.f/2048.f);
    const float var = stat[256 + c] * (1.f/2048.f) - mu*mu;
    const float y = gamma[c] * (v - mu) * rsqrtf(var + 1e-5f) + beta[c];
    const float g = 0.5f * y * (1.f + erff(y * 0.70710678118654752f));
    out[idx] = x[idx] + g;
}

// ---- point_relation = E[:,0,:] * rc ----
__global__ __launch_bounds__(256) void k_pr(
    const short* __restrict__ ETb, const float* __restrict__ rc,
    float* __restrict__ out)
{
    const int i = blockIdx.x*256 + threadIdx.x;  // 2048
    const int b = i >> 9, m = i & 511;
    out[(size_t)4*256*512 + i] = bf2f(ETb[((size_t)b*512 + m)*512]) * rc[i];
}

extern "C" void kernel_launch(void* const* d_in, const int* in_sizes, int n_in,
                              void* d_out, int out_size, void* d_ws, size_t ws_size,
                              hipStream_t stream)
{
    const float* x         = (const float*)d_in[0];
    const float* pca       = (const float*)d_in[1];
    const float* angle_lrf = (const float*)d_in[2];
    const float* angle_pca = (const float*)d_in[3];
    const float* Wkp       = (const float*)d_in[4];
    const float* Wk        = (const float*)d_in[5];
    const float* Wv        = (const float*)d_in[6];
    const float* Wvp       = (const float*)d_in[7];
    const float* e1W       = (const float*)d_in[8];
    const float* e2W       = (const float*)d_in[10];
    const float* linW      = (const float*)d_in[12];
    const float* linb      = (const float*)d_in[13];
    const float* gamma     = (const float*)d_in[14];
    const float* beta      = (const float*)d_in[15];

    char* w = (char*)d_ws;
    float* P     = (float*)(w + 0);              // 4*704*512*4 = 5767168
    short* Wcatb = (short*)(w + 5767168);        // 720896
    short* InTb  = (short*)(w + 6488064);        // 2097152
    short* vsumb = (short*)(w + 8585216);        // 1048576
    short* ETb   = (short*)(w + 9633792);        // 2097152
    short* xrT   = (short*)(w + 11730944);       // 1048576
    float* rc    = (float*)(w + 12779520);       // 8192
    float* z     = (float*)(w + 12787712);       // 2097152
    float* stat  = (float*)(w + 14884864);       // 2048
    float* out   = (float*)d_out;

    k_prep_w <<<704,  256, 0, stream>>>(Wkp, Wk, Wv, Wvp, linW, e1W, Wcatb);
    k_prep_in<<<256,  256, 0, stream>>>(x, pca, InTb);
    k_gemm1  <<<704,  256, 0, stream>>>(Wcatb, InTb, P, vsumb);
    k_e2     <<<512,  256, 0, stream>>>(angle_pca, e2W, P);
    k_energy <<<512,  256, 0, stream>>>(P, angle_lrf, ETb);
    k_colsum <<<512,  256, 0, stream>>>(ETb, rc);
    k_xr2    <<<256,  256, 0, stream>>>(vsumb, ETb, rc, xrT);
    k_z2     <<<256,  256, 0, stream>>>(Wcatb, xrT, P, linb, z);
    k_stats  <<<256,  256, 0, stream>>>(z, stat);
    k_final  <<<2048, 256, 0, stream>>>(x, z, stat, gamma, beta, out);
    k_pr     <<<8,    256, 0, stream>>>(ETb, rc, out);
}

// Round 3
// 87.995 us; speedup vs baseline: 4.0599x; 1.2552x over previous
//
#include <hip/hip_runtime.h>
#include <math.h>

#define FCT 3.81971863420548805845f
#define DIVK 0.28782313662425575f

using bf16x8 = __attribute__((ext_vector_type(8))) short;
using f32x4  = __attribute__((ext_vector_type(4))) float;

__device__ inline short f2bf(float f) {
    union { float f; unsigned u; } v; v.f = f;
    unsigned r = v.u + 0x7FFFu + ((v.u >> 16) & 1u);
    return (short)(r >> 16);
}
__device__ inline float bf2f(short s) {
    union { unsigned u; float f; } v;
    v.u = ((unsigned)(unsigned short)s) << 16;
    return v.f;
}
__device__ inline unsigned pk2(float lo, float hi) {
    return ((unsigned)(unsigned short)f2bf(hi) << 16) | (unsigned)(unsigned short)f2bf(lo);
}

// ---- prep: Wcat bf16 [704][512]  +  InT bf16 [b][n][k] ----
__global__ __launch_bounds__(256) void k_prep(
    const float* __restrict__ Wkp, const float* __restrict__ Wk,
    const float* __restrict__ Wv, const float* __restrict__ Wvp,
    const float* __restrict__ linW, const float* __restrict__ e1W,
    const float* __restrict__ x, const float* __restrict__ pca,
    short* __restrict__ Wcatb, short* __restrict__ InTb)
{
    __shared__ float ts[64][65];
    const int bid = blockIdx.x;
    if (bid < 704) {
        const int r = bid;
        for (int k = threadIdx.x; k < 512; k += 256) {
            float v = 0.f;
            if (r < 64) { if (k < 256) v = Wkp[r*256 + k]; }
            else if (r < 128) { int o = r-64;  v = (k<256) ? Wk[o*256+k]  : Wkp[o*256 + k-256]; }
            else if (r < 384) { int o = r-128; v = (k<256) ? Wv[o*256+k]  : Wvp[o*256 + k-256]; }
            else if (r < 640) { int o = r-384; if (k<256) v = linW[o*256+k]; }
            else {
                int o = r-640;
                if (k < 256) {
                    float a = 0.f;
                    for (int j = 0; j < 64; ++j) a = fmaf(e1W[j*64 + o], Wkp[j*256 + k], a);
                    v = a;
                }
            }
            Wcatb[(size_t)r*512 + k] = f2bf(v);
        }
    } else {
        const int id = bid - 704;             // 4b x 8kt x 8nt
        const int b  = id >> 6;
        const int kt = (id >> 3) & 7;
        const int nt = id & 7;
        const int k0 = kt*64, n0 = nt*64;
        const float* src = (k0 < 256) ? (x + ((size_t)b*256 + k0)*512)
                                      : (pca + ((size_t)b*256 + (k0-256))*512);
        #pragma unroll
        for (int i = 0; i < 16; ++i) {
            int idx = threadIdx.x + 256*i;
            int r = idx >> 6, c = idx & 63;
            ts[r][c] = src[(size_t)r*512 + n0 + c];
        }
        __syncthreads();
        short* dst = InTb + (size_t)b*512*512;
        #pragma unroll
        for (int i = 0; i < 16; ++i) {
            int idx = threadIdx.x + 256*i;
            int n = idx >> 6, k = idx & 63;
            dst[(size_t)(n0+n)*512 + k0 + k] = f2bf(ts[k][n]);
        }
    }
}

// ---- big GEMM: Wcat @ [x;pca] -> xqb(bf16,T), Ktf(f32), vsumb(bf16), linx(f32), q1T(f32) ----
__global__ __launch_bounds__(256) void k_gemm1(
    const short* __restrict__ Wcatb, const short* __restrict__ InTb,
    short* __restrict__ xqb, float* __restrict__ Ktf, short* __restrict__ vsumb,
    float* __restrict__ linx, float* __restrict__ q1T)
{
    const int bid = blockIdx.x;            // 4 x 11 x 16 = 704
    const int b  = bid / 176;
    const int rt = (bid / 16) % 11;
    const int ct = bid % 16;
    const int r0 = rt*64, c0 = ct*32;
    const int w = threadIdx.x >> 6, lane = threadIdx.x & 63;
    const int lr = lane & 15, lg = lane >> 4;

    const short* ap  = Wcatb + (size_t)(r0 + w*16 + lr)*512 + 8*lg;
    const short* bp0 = InTb + (size_t)b*512*512 + (size_t)(c0 + lr)*512 + 8*lg;
    const short* bp1 = bp0 + 16*512;

    f32x4 acc0 = {0.f,0.f,0.f,0.f}, acc1 = {0.f,0.f,0.f,0.f};
    #pragma unroll 4
    for (int kk = 0; kk < 512; kk += 32) {
        bf16x8 a  = *(const bf16x8*)(ap  + kk);
        bf16x8 b0 = *(const bf16x8*)(bp0 + kk);
        bf16x8 b1 = *(const bf16x8*)(bp1 + kk);
        acc0 = __builtin_amdgcn_mfma_f32_16x16x32_bf16(a, b0, acc0, 0, 0, 0);
        acc1 = __builtin_amdgcn_mfma_f32_16x16x32_bf16(a, b1, acc1, 0, 0, 0);
    }
    const int rowb = r0 + w*16 + lg*4;
    const int col0 = c0 + lr;
    if (r0 == 0) {                 // xq -> bf16 transposed [n][o]
        #pragma unroll
        for (int j = 0; j < 4; ++j) {
            xqb[((size_t)b*512 + col0)*64 + rowb + j]      = f2bf(acc0[j]);
            xqb[((size_t)b*512 + col0 + 16)*64 + rowb + j] = f2bf(acc1[j]);
        }
    } else if (r0 == 64) {         // Kt f32 [o][m]
        #pragma unroll
        for (int j = 0; j < 4; ++j) {
            Ktf[((size_t)b*64 + rowb-64 + j)*512 + col0]      = acc0[j];
            Ktf[((size_t)b*64 + rowb-64 + j)*512 + col0 + 16] = acc1[j];
        }
    } else if (r0 < 384) {         // vsum bf16 [o][n]
        #pragma unroll
        for (int j = 0; j < 4; ++j) {
            vsumb[((size_t)b*256 + rowb-128 + j)*512 + col0]      = f2bf(acc0[j]);
            vsumb[((size_t)b*256 + rowb-128 + j)*512 + col0 + 16] = f2bf(acc1[j]);
        }
    } else if (r0 < 640) {         // linW@x f32 [o][n]
        #pragma unroll
        for (int j = 0; j < 4; ++j) {
            linx[((size_t)b*256 + rowb-384 + j)*512 + col0]      = acc0[j];
            linx[((size_t)b*256 + rowb-384 + j)*512 + col0 + 16] = acc1[j];
        }
    } else {                       // q1 f32 transposed [n][o]
        #pragma unroll
        for (int j = 0; j < 4; ++j) {
            q1T[((size_t)b*512 + col0)*64 + rowb-640 + j]      = acc0[j];
            q1T[((size_t)b*512 + col0 + 16)*64 + rowb-640 + j] = acc1[j];
        }
    }
}

// ---- e2 fold + transpose: KtT[b][m][o] = bf16(Ktf[o][m] + e2W[o]·emb(angle_pca[m])) ----
__global__ __launch_bounds__(256) void k_e2t(
    const float* __restrict__ angle_pca, const float* __restrict__ e2W,
    const float* __restrict__ Ktf, short* __restrict__ KtT)
{
    const int b  = blockIdx.x >> 3;        // 4 x 8
    const int m0 = (blockIdx.x & 7) * 64;
    __shared__ float emb_s[64][65];
    __shared__ float e2w_s[64][65];
    const int t = threadIdx.x;
    #pragma unroll
    for (int i = 0; i < 16; ++i) {
        int idx = t + 256*i;
        e2w_s[idx >> 6][idx & 63] = e2W[idx];
    }
    {
        const int m = t >> 2, q = t & 3;
        const float a = angle_pca[b*512 + m0 + m] * FCT;
        #pragma unroll
        for (int i = q*8; i < q*8+8; ++i) {
            float arg = a * __expf(-(float)i * DIVK);
            emb_s[m][2*i]   = __sinf(arg);
            emb_s[m][2*i+1] = __cosf(arg);
        }
    }
    __syncthreads();
    const int o = t & 63, wid = t >> 6;
    for (int mi = wid; mi < 64; mi += 4) {
        float acc = Ktf[((size_t)b*64 + o)*512 + m0 + mi];
        #pragma unroll 8
        for (int k = 0; k < 64; ++k) acc = fmaf(e2w_s[o][k], emb_s[mi][k], acc);
        KtT[((size_t)b*512 + m0 + mi)*64 + o] = f2bf(acc);
    }
}

// ---- QK^T MFMA: S[b][n][m] = xq[n]·Kt[:,m], K=64 ----
__global__ __launch_bounds__(256) void k_qk(
    const short* __restrict__ xqb, const short* __restrict__ KtT,
    float* __restrict__ S)
{
    const int bid = blockIdx.x;            // 4 x 8 x 16 = 512
    const int b  = bid / 128;
    const int rt = (bid / 16) % 8;
    const int ct = bid % 16;
    const int r0 = rt*64, c0 = ct*32;
    const int w = threadIdx.x >> 6, lane = threadIdx.x & 63;
    const int lr = lane & 15, lg = lane >> 4;
    const short* ap  = xqb + ((size_t)b*512 + r0 + w*16 + lr)*64 + 8*lg;
    const short* bp0 = KtT + ((size_t)b*512 + c0 + lr)*64 + 8*lg;
    const short* bp1 = bp0 + 16*64;
    f32x4 acc0 = {0.f,0.f,0.f,0.f}, acc1 = {0.f,0.f,0.f,0.f};
    #pragma unroll
    for (int kk = 0; kk < 64; kk += 32) {
        bf16x8 a  = *(const bf16x8*)(ap  + kk);
        bf16x8 b0 = *(const bf16x8*)(bp0 + kk);
        bf16x8 b1 = *(const bf16x8*)(bp1 + kk);
        acc0 = __builtin_amdgcn_mfma_f32_16x16x32_bf16(a, b0, acc0, 0, 0, 0);
        acc1 = __builtin_amdgcn_mfma_f32_16x16x32_bf16(a, b1, acc1, 0, 0, 0);
    }
    const int rowb = r0 + w*16 + lg*4;
    const int col0 = c0 + lr;
    float* Sb = S + (size_t)b*512*512;
    #pragma unroll
    for (int j = 0; j < 4; ++j) {
        Sb[(size_t)(rowb+j)*512 + col0]      = acc0[j];
        Sb[(size_t)(rowb+j)*512 + col0 + 16] = acc1[j];
    }
}

// ---- sincos energy + row softmax; 4 rows/block, 2 m/thread; writes ET[m][n] bf16 ----
__global__ __launch_bounds__(256) void k_energy2(
    const float* __restrict__ S, const float* __restrict__ q1T,
    const float* __restrict__ angle_lrf, short* __restrict__ ETb)
{
    const int b  = blockIdx.x >> 7;        // 4 x 128
    const int n0 = (blockIdx.x & 127) * 4;
    __shared__ float qs[4][64];
    __shared__ float divs[32];
    __shared__ float4 red[256];
    const int t = threadIdx.x;
    if (t < 64) {
        #pragma unroll
        for (int i = 0; i < 4; ++i) qs[i][t] = q1T[((size_t)b*512 + n0 + i)*64 + t];
    } else if (t < 96) {
        divs[t-64] = __expf(-(float)(t-64) * DIVK);
    }
    __syncthreads();
    float acc[4][2], av[4][2];
    #pragma unroll
    for (int i = 0; i < 4; ++i) {
        const float2 sv = *(const float2*)&S[((size_t)b*512 + n0 + i)*512 + 2*t];
        const float2 an = *(const float2*)&angle_lrf[((size_t)b*512 + n0 + i)*512 + 2*t];
        acc[i][0] = sv.x; acc[i][1] = sv.y;
        av[i][0] = an.x * FCT; av[i][1] = an.y * FCT;
    }
    for (int j = 0; j < 32; ++j) {
        const float d = divs[j];
        const float w0 = qs[0][2*j], w1 = qs[0][2*j+1];
        const float u0 = qs[1][2*j], u1 = qs[1][2*j+1];
        const float v0 = qs[2][2*j], v1 = qs[2][2*j+1];
        const float y0 = qs[3][2*j], y1 = qs[3][2*j+1];
        #pragma unroll
        for (int m = 0; m < 2; ++m) {
            float a0 = av[0][m]*d, a1 = av[1][m]*d, a2 = av[2][m]*d, a3 = av[3][m]*d;
            acc[0][m] = fmaf(w0, __sinf(a0), fmaf(w1, __cosf(a0), acc[0][m]));
            acc[1][m] = fmaf(u0, __sinf(a1), fmaf(u1, __cosf(a1), acc[1][m]));
            acc[2][m] = fmaf(v0, __sinf(a2), fmaf(v1, __cosf(a2), acc[2][m]));
            acc[3][m] = fmaf(y0, __sinf(a3), fmaf(y1, __cosf(a3), acc[3][m]));
        }
    }
    float4 v;
    v.x = fmaxf(acc[0][0], acc[0][1]); v.y = fmaxf(acc[1][0], acc[1][1]);
    v.z = fmaxf(acc[2][0], acc[2][1]); v.w = fmaxf(acc[3][0], acc[3][1]);
    red[t] = v; __syncthreads();
    for (int s = 128; s > 0; s >>= 1) {
        if (t < s) {
            float4 o = red[t+s], m2 = red[t];
            m2.x = fmaxf(m2.x,o.x); m2.y = fmaxf(m2.y,o.y);
            m2.z = fmaxf(m2.z,o.z); m2.w = fmaxf(m2.w,o.w);
            red[t] = m2;
        }
        __syncthreads();
    }
    const float4 mx = red[0]; __syncthreads();
    float p[4][2];
    p[0][0] = __expf(acc[0][0]-mx.x); p[0][1] = __expf(acc[0][1]-mx.x);
    p[1][0] = __expf(acc[1][0]-mx.y); p[1][1] = __expf(acc[1][1]-mx.y);
    p[2][0] = __expf(acc[2][0]-mx.z); p[2][1] = __expf(acc[2][1]-mx.z);
    p[3][0] = __expf(acc[3][0]-mx.w); p[3][1] = __expf(acc[3][1]-mx.w);
    v.x = p[0][0]+p[0][1]; v.y = p[1][0]+p[1][1];
    v.z = p[2][0]+p[2][1]; v.w = p[3][0]+p[3][1];
    red[t] = v; __syncthreads();
    for (int s = 128; s > 0; s >>= 1) {
        if (t < s) {
            float4 o = red[t+s];
            red[t].x += o.x; red[t].y += o.y; red[t].z += o.z; red[t].w += o.w;
        }
        __syncthreads();
    }
    const float4 tot = red[0];
    const float i0 = 1.f/tot.x, i1 = 1.f/tot.y, i2 = 1.f/tot.z, i3 = 1.f/tot.w;
    short* Eb = ETb + (size_t)b*512*512;
    #pragma unroll
    for (int m = 0; m < 2; ++m) {
        uint2 u;
        u.x = pk2(p[0][m]*i0, p[1][m]*i1);
        u.y = pk2(p[2][m]*i2, p[3][m]*i3);
        *(uint2*)(Eb + (size_t)(2*t + m)*512 + n0) = u;
    }
}

// ---- column sums of E (= row sums of ET) -> rc; fused point_relation ----
__global__ __launch_bounds__(256) void k_colsum(
    const short* __restrict__ ETb, float* __restrict__ rc, float* __restrict__ out)
{
    const int row  = blockIdx.x*4 + (threadIdx.x >> 6);   // b*512+m, 2048 total
    const int lane = threadIdx.x & 63;
    const uint4 u4 = *(const uint4*)(ETb + (size_t)row*512 + lane*8);
    float s = 0.f;
    unsigned uu[4] = {u4.x, u4.y, u4.z, u4.w};
    #pragma unroll
    for (int i = 0; i < 4; ++i) {
        union { unsigned u; float f; } lo, hi;
        lo.u = uu[i] << 16; hi.u = uu[i] & 0xFFFF0000u;
        s += lo.f + hi.f;
    }
    #pragma unroll
    for (int off = 32; off > 0; off >>= 1) s += __shfl_xor(s, off, 64);
    if (lane == 0) {
        const float r = 1.f / (1e-12f + s);
        rc[row] = r;
        out[(size_t)4*256*512 + row] = bf2f((short)(u4.x & 0xFFFFu)) * r;  // E[:,0,:]*rc
    }
}

// ---- xr = 0.5*rc[m]*(vsum @ E), MFMA, store transposed bf16 xrT[m][o] ----
__global__ __launch_bounds__(256) void k_xr2(
    const short* __restrict__ vsumb, const short* __restrict__ ETb,
    const float* __restrict__ rc, short* __restrict__ xrT)
{
    const int bid = blockIdx.x;            // 4 x 4 x 16 = 256
    const int b  = bid / 64;
    const int rt = (bid / 16) % 4;
    const int ct = bid % 16;
    const int r0 = rt*64, c0 = ct*32;
    const int w = threadIdx.x >> 6, lane = threadIdx.x & 63;
    const int lr = lane & 15, lg = lane >> 4;
    const short* ap  = vsumb + (size_t)b*256*512 + (size_t)(r0 + w*16 + lr)*512 + 8*lg;
    const short* bp0 = ETb + (size_t)b*512*512 + (size_t)(c0 + lr)*512 + 8*lg;
    const short* bp1 = bp0 + 16*512;
    f32x4 acc0 = {0.f,0.f,0.f,0.f}, acc1 = {0.f,0.f,0.f,0.f};
    #pragma unroll 4
    for (int kk = 0; kk < 512; kk += 32) {
        bf16x8 a  = *(const bf16x8*)(ap  + kk);
        bf16x8 b0 = *(const bf16x8*)(bp0 + kk);
        bf16x8 b1 = *(const bf16x8*)(bp1 + kk);
        acc0 = __builtin_amdgcn_mfma_f32_16x16x32_bf16(a, b0, acc0, 0, 0, 0);
        acc1 = __builtin_amdgcn_mfma_f32_16x16x32_bf16(a, b1, acc1, 0, 0, 0);
    }
    const int rowb = r0 + w*16 + lg*4;     // o base
    const int m0 = c0 + lr, m1 = m0 + 16;
    const float s0 = 0.5f * rc[b*512 + m0];
    const float s1 = 0.5f * rc[b*512 + m1];
    short* xb = xrT + (size_t)b*512*256;
    uint2 u;
    u.x = pk2(acc0[0]*s0, acc0[1]*s0);
    u.y = pk2(acc0[2]*s0, acc0[3]*s0);
    *(uint2*)(xb + (size_t)m0*256 + rowb) = u;
    u.x = pk2(acc1[0]*s1, acc1[1]*s1);
    u.y = pk2(acc1[2]*s1, acc1[3]*s1);
    *(uint2*)(xb + (size_t)m1*256 + rowb) = u;
}

// ---- z = linx - linW @ xr + lin_b ----
__global__ __launch_bounds__(256) void k_z2(
    const short* __restrict__ Wcatb, const short* __restrict__ xrT,
    const float* __restrict__ linx, const float* __restrict__ lin_b,
    float* __restrict__ z)
{
    const int bid = blockIdx.x;            // 4 x 4 x 16 = 256
    const int b  = bid / 64;
    const int rt = (bid / 16) % 4;
    const int ct = bid % 16;
    const int r0 = rt*64, c0 = ct*32;
    const int w = threadIdx.x >> 6, lane = threadIdx.x & 63;
    const int lr = lane & 15, lg = lane >> 4;
    const short* ap  = Wcatb + (size_t)(384 + r0 + w*16 + lr)*512 + 8*lg;
    const short* bp0 = xrT + (size_t)b*512*256 + (size_t)(c0 + lr)*256 + 8*lg;
    const short* bp1 = bp0 + 16*256;
    f32x4 acc0 = {0.f,0.f,0.f,0.f}, acc1 = {0.f,0.f,0.f,0.f};
    #pragma unroll
    for (int kk = 0; kk < 256; kk += 32) {
        bf16x8 a  = *(const bf16x8*)(ap  + kk);
        bf16x8 b0 = *(const bf16x8*)(bp0 + kk);
        bf16x8 b1 = *(const bf16x8*)(bp1 + kk);
        acc0 = __builtin_amdgcn_mfma_f32_16x16x32_bf16(a, b0, acc0, 0, 0, 0);
        acc1 = __builtin_amdgcn_mfma_f32_16x16x32_bf16(a, b1, acc1, 0, 0, 0);
    }
    const int rowb = r0 + w*16 + lg*4;
    const int col0 = c0 + lr;
    const float* Lb = linx + (size_t)b*256*512;
    float* zb = z + (size_t)b*256*512;
    #pragma unroll
    for (int j = 0; j < 4; ++j) {
        float lb = lin_b[rowb+j];
        zb[(size_t)(rowb+j)*512 + col0]      = Lb[(size_t)(rowb+j)*512 + col0]      - acc0[j] + lb;
        zb[(size_t)(rowb+j)*512 + col0 + 16] = Lb[(size_t)(rowb+j)*512 + col0 + 16] - acc1[j] + lb;
    }
}

// ---- BN stats per channel ----
__global__ __launch_bounds__(256) void k_stats(
    const float* __restrict__ z, float* __restrict__ stat)
{
    const int c = blockIdx.x;
    const int t = threadIdx.x;
    float s = 0.f, s2 = 0.f;
    for (int i = t; i < 2048; i += 256) {
        int b = i >> 9, n = i & 511;
        float v = z[((size_t)b*256 + c)*512 + n];
        s += v; s2 = fmaf(v, v, s2);
    }
    __shared__ float r1[256], r2[256];
    r1[t] = s; r2[t] = s2;
    __syncthreads();
    for (int st = 128; st > 0; st >>= 1) {
        if (t < st) { r1[t] += r1[t+st]; r2[t] += r2[t+st]; }
        __syncthreads();
    }
    if (t == 0) { stat[c] = r1[0]; stat[256 + c] = r2[0]; }
}

// ---- BN apply + exact gelu + residual (float4) ----
__global__ __launch_bounds__(256) void k_final(
    const float* __restrict__ x, const float* __restrict__ z,
    const float* __restrict__ stat, const float* __restrict__ gamma,
    const float* __restrict__ beta, float* __restrict__ out)
{
    const int gid = blockIdx.x*256 + threadIdx.x;   // 131072 (x4 elems)
    const int base = gid * 4;
    const int c = (base >> 9) & 255;
    const float mu  = stat[c] * (1.f/2048.f);
    const float var = stat[256 + c] * (1.f/2048.f) - mu*mu;
    const float gsc = gamma[c] * rsqrtf(var + 1e-5f);
    const float bt  = beta[c];
    const float4 zv = *(const float4*)&z[base];
    const float4 xv = *(const float4*)&x[base];
    float4 ov;
    {
        float y = (zv.x - mu)*gsc + bt;
        ov.x = xv.x + 0.5f*y*(1.f + erff(y*0.70710678118654752f));
        y = (zv.y - mu)*gsc + bt;
        ov.y = xv.y + 0.5f*y*(1.f + erff(y*0.70710678118654752f));
        y = (zv.z - mu)*gsc + bt;
        ov.z = xv.z + 0.5f*y*(1.f + erff(y*0.70710678118654752f));
        y = (zv.w - mu)*gsc + bt;
        ov.w = xv.w + 0.5f*y*(1.f + erff(y*0.70710678118654752f));
    }
    *(float4*)&out[base] = ov;
}

extern "C" void kernel_launch(void* const* d_in, const int* in_sizes, int n_in,
                              void* d_out, int out_size, void* d_ws, size_t ws_size,
                              hipStream_t stream)
{
    const float* x         = (const float*)d_in[0];
    const float* pca       = (const float*)d_in[1];
    const float* angle_lrf = (const float*)d_in[2];
    const float* angle_pca = (const float*)d_in[3];
    const float* Wkp       = (const float*)d_in[4];
    const float* Wk        = (const float*)d_in[5];
    const float* Wv        = (const float*)d_in[6];
    const float* Wvp       = (const float*)d_in[7];
    const float* e1W       = (const float*)d_in[8];
    const float* e2W       = (const float*)d_in[10];
    const float* linW      = (const float*)d_in[12];
    const float* linb      = (const float*)d_in[13];
    const float* gamma     = (const float*)d_in[14];
    const float* beta      = (const float*)d_in[15];

    char* w = (char*)d_ws;
    short* Wcatb = (short*)(w + 0);          //   720896
    short* InTb  = (short*)(w + 720896);     //  2097152
    short* vsumb = (short*)(w + 2818048);    //  1048576
    short* KtT   = (short*)(w + 3866624);    //   262144
    short* ETb   = (short*)(w + 4128768);    //  2097152
    float* rc    = (float*)(w + 6225920);    //     8192
    short* xrT   = (short*)(w + 6234112);    //  1048576
    float* stat  = (float*)(w + 7282688);    //     2048
    float* S     = (float*)(w + 7284736);    //  4194304 (Ktf aliases base; z aliases base later)
    float* Ktf   = (float*)(w + 7284736);    //   524288  (dead before S written)
    float* z     = (float*)(w + 7284736);    //  2097152  (written after S last read)
    short* xqb   = (short*)(w + 11479040);   //   262144
    float* q1T   = (float*)(w + 11741184);   //  1048576
    float* linx  = (float*)(w + 12789760);   //  2097152  -> end 14886912
    float* out   = (float*)d_out;

    k_prep   <<<960, 256, 0, stream>>>(Wkp, Wk, Wv, Wvp, linW, e1W, x, pca, Wcatb, InTb);
    k_gemm1  <<<704, 256, 0, stream>>>(Wcatb, InTb, xqb, Ktf, vsumb, linx, q1T);
    k_e2t    <<<32,  256, 0, stream>>>(angle_pca, e2W, Ktf, KtT);
    k_qk     <<<512, 256, 0, stream>>>(xqb, KtT, S);
    k_energy2<<<512, 256, 0, stream>>>(S, q1T, angle_lrf, ETb);
    k_colsum <<<512, 256, 0, stream>>>(ETb, rc, out);
    k_xr2    <<<256, 256, 0, stream>>>(vsumb, ETb, rc, xrT);
    k_z2     <<<256, 256, 0, stream>>>(Wcatb, xrT, linx, linb, z);
    k_stats  <<<256, 256, 0, stream>>>(z, stat);
    k_final  <<<512, 256, 0, stream>>>(x, z, stat, gamma, beta, out);
}